// Round 3
// baseline (2484.248 us; speedup 1.0000x reference)
//
#include <hip/hip_runtime.h>
#include <stdint.h>

#define T_TOK 4096
#define HDIM 2048
#define MDIM 1408
#define NEXP 28
#define TOPK 6
#define NPAIR (T_TOK*TOPK)   // 24576

typedef unsigned short u16;
typedef short short8 __attribute__((ext_vector_type(8)));
typedef float f32x4 __attribute__((ext_vector_type(4)));

__device__ __forceinline__ u16 f2bf(float x){
  unsigned int u = __float_as_uint(x);
  u += 0x7fffu + ((u >> 16) & 1u);
  return (u16)(u >> 16);
}
__device__ __forceinline__ float bf2f(unsigned int h){
  return __uint_as_float(h << 16);
}

__device__ __forceinline__ void gload16(const u16* g, u16* l){
  __builtin_amdgcn_global_load_lds((const __attribute__((address_space(1))) unsigned int*)g,
                                   (__attribute__((address_space(3))) unsigned int*)l,
                                   16, 0, 0);
}

// ---------------- x fp32 -> bf16 ----------------
__global__ __launch_bounds__(256) void cvt_kernel(const float* __restrict__ x,
                                                  u16* __restrict__ xb, int n8){
  int i = blockIdx.x*256 + threadIdx.x;
  if (i >= n8) return;
  const float4* s = (const float4*)x + (size_t)i*2;
  float4 a = s[0], b = s[1];
  unsigned int w0 = (unsigned)f2bf(a.x) | ((unsigned)f2bf(a.y)<<16);
  unsigned int w1 = (unsigned)f2bf(a.z) | ((unsigned)f2bf(a.w)<<16);
  unsigned int w2 = (unsigned)f2bf(b.x) | ((unsigned)f2bf(b.y)<<16);
  unsigned int w3 = (unsigned)f2bf(b.z) | ((unsigned)f2bf(b.w)<<16);
  uint4 o = {w0,w1,w2,w3};
  ((uint4*)xb)[i] = o;
}

// ---------------- transpose + convert: in [E][K][N] fp32 -> out [E][N][K] bf16 ----------------
// 64x64 tiles; 16B vectorized on both sides.
__global__ __launch_bounds__(256) void transpose_cvt(const float* __restrict__ in,
                                                     u16* __restrict__ out, int K, int N){
  const int e = blockIdx.z;
  const int n0 = blockIdx.x*64, k0 = blockIdx.y*64;
  const float* src = in + ((size_t)e*K + k0)*N + n0;
  u16* dst = out + ((size_t)e*N + n0)*K + k0;
  __shared__ u16 td[64][72];
  const int tid = threadIdx.x;
  const int rk = tid>>4, rn = (tid&15)*4;
  #pragma unroll
  for (int i=0;i<4;i++){
    int k = rk + 16*i;
    float4 v = *(const float4*)(src + (size_t)k*N + rn);
    td[k][rn+0]=f2bf(v.x); td[k][rn+1]=f2bf(v.y);
    td[k][rn+2]=f2bf(v.z); td[k][rn+3]=f2bf(v.w);
  }
  __syncthreads();
  const int k8 = (tid&7)*8;
  #pragma unroll
  for (int i=0;i<2;i++){
    int n = (tid>>3) + 32*i;
    unsigned int w[4];
    #pragma unroll
    for (int j=0;j<4;j++)
      w[j] = (unsigned)td[k8+2*j][n] | ((unsigned)td[k8+2*j+1][n]<<16);
    uint4 o = {w[0],w[1],w[2],w[3]};
    *(uint4*)(dst + (size_t)n*K + k8) = o;
  }
}

// ---------------- gating: logits -> softmax -> top6 ----------------
__global__ __launch_bounds__(256) void gate_kernel(const float* __restrict__ x,
                                                   const float* __restrict__ gw,
                                                   int* __restrict__ topk_idx,
                                                   float* __restrict__ topk_w,
                                                   int* __restrict__ counts){
  const int wave = threadIdx.x >> 6, lane = threadIdx.x & 63;
  const int t = blockIdx.x*4 + wave;
  const float* xr = x + (size_t)t*HDIM;
  float xv[32];
  #pragma unroll
  for (int i=0;i<32;i++) xv[i] = xr[lane + 64*i];
  float sc[NEXP];
  #pragma unroll
  for (int e=0;e<NEXP;e++){
    const float* g = gw + (size_t)e*HDIM + lane;
    float a = 0.f;
    #pragma unroll
    for (int i=0;i<32;i++) a += xv[i]*g[64*i];
    #pragma unroll
    for (int d=32; d>0; d>>=1) a += __shfl_xor(a, d);
    sc[e] = a;
  }
  float mx = sc[0];
  #pragma unroll
  for (int e=1;e<NEXP;e++) mx = fmaxf(mx, sc[e]);
  unsigned int mask=0; int bi[TOPK]; float bs[TOPK]; float bsum=0.f;
  #pragma unroll
  for (int k=0;k<TOPK;k++){
    float bm=-3.4e38f; int bj=0;
    #pragma unroll
    for (int e=0;e<NEXP;e++){
      bool ok = (((mask>>e)&1u)==0u) && (sc[e]>bm);
      bm = ok ? sc[e] : bm; bj = ok ? e : bj;
    }
    mask |= (1u<<bj);
    float s = expf(bm - mx);
    bi[k]=bj; bs[k]=s; bsum+=s;
  }
  if (lane==0){
    float inv = 1.f/(bsum + 1e-20f);
    #pragma unroll
    for (int k=0;k<TOPK;k++){
      topk_idx[t*TOPK+k]=bi[k];
      topk_w[t*TOPK+k]=bs[k]*inv;
      atomicAdd(&counts[bi[k]],1);
    }
  }
}

// ---------------- scan + fill dispatch lists ----------------
__global__ void scan_kernel(const int* __restrict__ counts, int* __restrict__ offsets,
                            int* __restrict__ cursor){
  int t = threadIdx.x;
  if (t < NEXP) cursor[t] = 0;
  if (t == 0){
    int s = 0;
    for (int e=0;e<NEXP;e++){ offsets[e]=s; s+=counts[e]; }
    offsets[NEXP]=s;
  }
}

__global__ __launch_bounds__(256) void fill_kernel(const int* __restrict__ topk_idx,
                                                   const float* __restrict__ topk_w,
                                                   const int* __restrict__ offsets,
                                                   int* __restrict__ cursor,
                                                   int* __restrict__ pair_token,
                                                   int* __restrict__ pos){
  int t = blockIdx.x*256 + threadIdx.x;
  if (t >= T_TOK) return;
  #pragma unroll
  for (int k=0;k<TOPK;k++){
    int e = topk_idx[t*TOPK+k];
    int c = atomicAdd(&cursor[e],1);
    int p = offsets[e]+c;
    pair_token[p]=t;
    pos[t*TOPK+k]=p;
  }
}

// ---------------- grouped GEMM: BK=32, double-buffered, counted vmcnt ----------------
// A rows bf16 [*,K]; B [E][N][K] bf16. Tile 128x128, 4 waves 2x2.
// Row-pair swizzle: 2 rows (128B) = 8 chunk slots; slot = ((r&1)<<2 | g) ^ ((r>>1)&7).
// EPI 0 (NB=2): h = silu(acc0)*acc1 -> Hout bf16 rows.  EPI 1 (NB=1): acc0 -> Hout bf16 rows.
template<int NB, bool GATHER, int EPI>
__global__ __launch_bounds__(256,2) void gemm3(
    const u16* __restrict__ Ab, const u16* __restrict__ B0, const u16* __restrict__ B1,
    u16* __restrict__ Hout,
    const int* __restrict__ counts, const int* __restrict__ offsets,
    const int* __restrict__ pair_token,
    int K, int N)
{
  const int e = blockIdx.z;
  const int cnt = counts[e];
  const int row0 = blockIdx.x*128;      // x = row-block (innermost -> B-panel locality)
  if (row0 >= cnt) return;
  const int off = offsets[e];
  const int n0 = blockIdx.y*128;

  __shared__ u16 smem[2*(1+NB)*4096];   // [buf][A|B0|(B1)] 8KB tiles

  const int tid = threadIdx.x;
  const int lane = tid&63, wid = tid>>6;
  const int wm = wid>>1, wn = wid&1;
  const int lrow = lane&15, lgrp = lane>>4;

  // staging sources: chunk c -> (group G=c>>3, slot s=c&7); global u = s ^ (G&7)
  const u16* ap[2]; const u16* bp0[2]; const u16* bp1[2];
  #pragma unroll
  for (int j=0;j<2;j++){
    int c = tid + 256*j;
    int G = c>>3, s = c&7;
    int u = s ^ (G&7);
    int r = 2*G + (u>>2);
    int g = u&3;
    int pr = off + min(row0 + r, cnt-1);
    const u16* arow = GATHER ? (Ab + (size_t)pair_token[pr]*K) : (Ab + (size_t)pr*K);
    ap[j] = arow + g*8;
    size_t brow = (size_t)e*N + (size_t)(n0 + r);
    bp0[j] = B0 + brow*K + g*8;
    if (NB==2) bp1[j] = B1 + brow*K + g*8;
  }

  // fragment LDS offsets (u16 units)
  int aoff[4], boff[4];
  #pragma unroll
  for (int f=0;f<4;f++){
    int mr = wm*64 + f*16 + lrow;
    aoff[f] = (mr>>1)*64 + (((((mr&1)<<2)|lgrp) ^ ((mr>>1)&7))*8);
    int nr = wn*64 + f*16 + lrow;
    boff[f] = (nr>>1)*64 + (((((nr&1)<<2)|lgrp) ^ ((nr>>1)&7))*8);
  }

  f32x4 acc0[4][4] = {};
  f32x4 acc1[4][4] = {};

  const int nt = K/32;
  const int TB = (1+NB)*4096;
  // prologue: stage tile 0 -> buf 0
  #pragma unroll
  for (int j=0;j<2;j++){
    int ldo = (tid + 256*j)*8;
    gload16(ap[j], &smem[ldo]);
    gload16(bp0[j], &smem[4096+ldo]);
    if (NB==2) gload16(bp1[j], &smem[8192+ldo]);
  }

  for (int t=0; t<nt; ++t){
    const int cur = (t&1)*TB;
    const int nxt = ((t+1)&1)*TB;
    if (t+1 < nt){
      const int kt = (t+1)*32;
      #pragma unroll
      for (int j=0;j<2;j++){
        int ldo = (tid + 256*j)*8;
        gload16(ap[j] + kt, &smem[nxt + ldo]);
        gload16(bp0[j] + kt, &smem[nxt + 4096 + ldo]);
        if (NB==2) gload16(bp1[j] + kt, &smem[nxt + 8192 + ldo]);
      }
      if (NB==2) asm volatile("s_waitcnt vmcnt(6)" ::: "memory");
      else       asm volatile("s_waitcnt vmcnt(4)" ::: "memory");
    } else {
      asm volatile("s_waitcnt vmcnt(0)" ::: "memory");
    }
    __builtin_amdgcn_s_barrier();

    short8 af[4], b0f[4], b1f[4];
    #pragma unroll
    for (int f=0;f<4;f++){
      af[f]  = *(const short8*)&smem[cur + aoff[f]];
      b0f[f] = *(const short8*)&smem[cur + 4096 + boff[f]];
      if (NB==2) b1f[f] = *(const short8*)&smem[cur + 8192 + boff[f]];
    }
    #pragma unroll
    for (int fm=0;fm<4;fm++){
      #pragma unroll
      for (int fn=0;fn<4;fn++){
        acc0[fm][fn] = __builtin_amdgcn_mfma_f32_16x16x32_bf16(af[fm], b0f[fn], acc0[fm][fn],0,0,0);
        if (NB==2)
          acc1[fm][fn] = __builtin_amdgcn_mfma_f32_16x16x32_bf16(af[fm], b1f[fn], acc1[fm][fn],0,0,0);
      }
    }
    __builtin_amdgcn_s_barrier();
  }

  #pragma unroll
  for (int fm=0;fm<4;fm++){
    #pragma unroll
    for (int j=0;j<4;j++){
      int grow = wm*64 + fm*16 + lgrp*4 + j;
      if (row0+grow < cnt){
        int p = off + row0 + grow;
        u16* hrow = Hout + (size_t)p*N;
        #pragma unroll
        for (int fn=0;fn<4;fn++){
          int col = n0 + wn*64 + fn*16 + lrow;
          if (EPI==0){
            float g = acc0[fm][fn][j], u = acc1[fm][fn][j];
            hrow[col] = f2bf(g*u/(1.f+expf(-g)));
          } else {
            hrow[col] = f2bf(acc0[fm][fn][j]);
          }
        }
      }
    }
  }
}

// ---------------- combine: out[t] = sum_k w[t,k] * pairbuf[pos[t,k]] ----------------
__global__ __launch_bounds__(256) void combine_kernel(const u16* __restrict__ pairbuf,
                                                      const int* __restrict__ pos,
                                                      const float* __restrict__ topk_w,
                                                      float* __restrict__ out){
  const int t = blockIdx.x;
  const int c = threadIdx.x*8;
  float acc[8] = {};
  #pragma unroll
  for (int k=0;k<TOPK;k++){
    int p = pos[t*TOPK+k];
    float w = topk_w[t*TOPK+k];
    uint4 v = *(const uint4*)&pairbuf[(size_t)p*HDIM + c];
    unsigned int ws_[4] = {v.x,v.y,v.z,v.w};
    #pragma unroll
    for (int j=0;j<4;j++){
      acc[2*j]   += w*bf2f(ws_[j]&0xffffu);
      acc[2*j+1] += w*bf2f(ws_[j]>>16);
    }
  }
  float4 o0 = {acc[0],acc[1],acc[2],acc[3]};
  float4 o1 = {acc[4],acc[5],acc[6],acc[7]};
  float* orow = out + (size_t)t*HDIM + c;
  *(float4*)orow = o0;
  *(float4*)(orow+4) = o1;
}

extern "C" void kernel_launch(void* const* d_in, const int* in_sizes, int n_in,
                              void* d_out, int out_size, void* d_ws, size_t ws_size,
                              hipStream_t stream) {
  const float* x  = (const float*)d_in[0];
  const float* gw = (const float*)d_in[1];
  const float* wg = (const float*)d_in[2];
  const float* wu = (const float*)d_in[3];
  const float* wd = (const float*)d_in[4];
  float* out = (float*)d_out;

  const size_t WT_BYTES = (size_t)NEXP*MDIM*HDIM*2;  // 161,480,704

  char* p = (char*)d_ws;
  u16* wg_t = (u16*)p;                 // [E][M][H] bf16
  u16* wd_t = (u16*)p;                 // [E][H][M] bf16 (overwrites wg_t after stage 1)
  p += WT_BYTES;
  u16* wu_t    = (u16*)p;              // [E][M][H] bf16
  u16* pairbuf = (u16*)p;              // [NPAIR][H] bf16 = 100.7 MB (overlays dead wu_t)
  p += WT_BYTES;
  u16* xb   = (u16*)p; p += (size_t)T_TOK*HDIM*2;   // 16.8 MB
  u16* hbuf = (u16*)p; p += (size_t)NPAIR*MDIM*2;   // 69.2 MB
  int*   topk_idx   = (int*)p;   p += NPAIR*4;
  float* topk_w     = (float*)p; p += NPAIR*4;
  int*   pair_token = (int*)p;   p += NPAIR*4;
  int*   pos        = (int*)p;   p += NPAIR*4;
  int*   counts     = (int*)p;   p += 128;
  int*   offsets    = (int*)p;   p += 128;
  int*   cursor     = (int*)p;   p += 128;

  hipMemsetAsync(counts, 0, 128, stream);
  cvt_kernel<<<T_TOK*HDIM/8/256, 256, 0, stream>>>(x, xb, T_TOK*HDIM/8);
  gate_kernel<<<T_TOK/4, 256, 0, stream>>>(x, gw, topk_idx, topk_w, counts);
  scan_kernel<<<1, 64, 0, stream>>>(counts, offsets, cursor);
  fill_kernel<<<T_TOK/256, 256, 0, stream>>>(topk_idx, topk_w, offsets, cursor, pair_token, pos);

  // weights -> bf16 transposed
  transpose_cvt<<<dim3(MDIM/64, HDIM/64, NEXP), 256, 0, stream>>>(wg, wg_t, HDIM, MDIM);
  transpose_cvt<<<dim3(MDIM/64, HDIM/64, NEXP), 256, 0, stream>>>(wu, wu_t, HDIM, MDIM);

  // stage 1: h = silu(x@wg) * (x@wu)   (fused, gathered A)
  gemm3<2,true,0><<<dim3(32, MDIM/128, NEXP), 256, 0, stream>>>(
      xb, wg_t, wu_t, hbuf, counts, offsets, pair_token, HDIM, MDIM);

  // wd -> bf16 transposed (reuses wg_t space; stream-ordered after stage 1)
  transpose_cvt<<<dim3(HDIM/64, MDIM/64, NEXP), 256, 0, stream>>>(wd, wd_t, MDIM, HDIM);

  // stage 2: pairbuf = h @ wd  (bf16 rows, overlays dead wu_t)
  gemm3<1,false,1><<<dim3(32, HDIM/128, NEXP), 256, 0, stream>>>(
      hbuf, wd_t, nullptr, pairbuf, counts, offsets, pair_token, MDIM, HDIM);

  // combine: out[t] = sum_k w_k * pairbuf[pos[t,k]]
  combine_kernel<<<T_TOK, 256, 0, stream>>>(pairbuf, pos, topk_w, out);
}

// Round 4
// 1042.945 us; speedup vs baseline: 2.3820x; 2.3820x over previous
//
#include <hip/hip_runtime.h>
#include <stdint.h>

#define T_TOK 4096
#define HDIM 2048
#define MDIM 1408
#define NEXP 28
#define TOPK 6
#define NPAIR (T_TOK*TOPK)   // 24576

typedef unsigned short u16;
typedef short short8 __attribute__((ext_vector_type(8)));
typedef float f32x4 __attribute__((ext_vector_type(4)));

__device__ __forceinline__ u16 f2bf(float x){
  unsigned int u = __float_as_uint(x);
  u += 0x7fffu + ((u >> 16) & 1u);
  return (u16)(u >> 16);
}
__device__ __forceinline__ float bf2f(unsigned int h){
  return __uint_as_float(h << 16);
}

__device__ __forceinline__ void gload16(const u16* g, u16* l){
  __builtin_amdgcn_global_load_lds((const __attribute__((address_space(1))) unsigned int*)g,
                                   (__attribute__((address_space(3))) unsigned int*)l,
                                   16, 0, 0);
}

// ---------------- x fp32 -> bf16 ----------------
__global__ __launch_bounds__(256) void cvt_kernel(const float* __restrict__ x,
                                                  u16* __restrict__ xb, int n8){
  int i = blockIdx.x*256 + threadIdx.x;
  if (i >= n8) return;
  const float4* s = (const float4*)x + (size_t)i*2;
  float4 a = s[0], b = s[1];
  unsigned int w0 = (unsigned)f2bf(a.x) | ((unsigned)f2bf(a.y)<<16);
  unsigned int w1 = (unsigned)f2bf(a.z) | ((unsigned)f2bf(a.w)<<16);
  unsigned int w2 = (unsigned)f2bf(b.x) | ((unsigned)f2bf(b.y)<<16);
  unsigned int w3 = (unsigned)f2bf(b.z) | ((unsigned)f2bf(b.w)<<16);
  uint4 o = {w0,w1,w2,w3};
  ((uint4*)xb)[i] = o;
}

// ---------------- transpose + convert: in [E][K][N] fp32 -> out [E][N][K] bf16 ----------------
// LDS stride 65 u16: 2-way bank aliasing (free) on both access patterns.
__global__ __launch_bounds__(256) void transpose_cvt(const float* __restrict__ in,
                                                     u16* __restrict__ out, int K, int N){
  const int e = blockIdx.z;
  const int n0 = blockIdx.x*64, k0 = blockIdx.y*64;
  const float* src = in + ((size_t)e*K + k0)*N + n0;
  u16* dst = out + ((size_t)e*N + n0)*K + k0;
  __shared__ u16 td[64][65];
  const int tid = threadIdx.x;
  const int rk = tid>>4, rn = (tid&15)*4;
  #pragma unroll
  for (int i=0;i<4;i++){
    int k = rk + 16*i;
    float4 v = *(const float4*)(src + (size_t)k*N + rn);
    td[k][rn+0]=f2bf(v.x); td[k][rn+1]=f2bf(v.y);
    td[k][rn+2]=f2bf(v.z); td[k][rn+3]=f2bf(v.w);
  }
  __syncthreads();
  const int k8 = (tid&7)*8;
  #pragma unroll
  for (int i=0;i<2;i++){
    int n = (tid>>3) + 32*i;
    unsigned int w[4];
    #pragma unroll
    for (int j=0;j<4;j++)
      w[j] = (unsigned)td[k8+2*j][n] | ((unsigned)td[k8+2*j+1][n]<<16);
    uint4 o = {w[0],w[1],w[2],w[3]};
    *(uint4*)(dst + (size_t)n*K + k8) = o;
  }
}

// ---------------- gating: logits -> softmax -> top6 ----------------
__global__ __launch_bounds__(256) void gate_kernel(const float* __restrict__ x,
                                                   const float* __restrict__ gw,
                                                   int* __restrict__ topk_idx,
                                                   float* __restrict__ topk_w,
                                                   int* __restrict__ counts){
  const int wave = threadIdx.x >> 6, lane = threadIdx.x & 63;
  const int t = blockIdx.x*4 + wave;
  const float* xr = x + (size_t)t*HDIM;
  float xv[32];
  #pragma unroll
  for (int i=0;i<32;i++) xv[i] = xr[lane + 64*i];
  float sc[NEXP];
  #pragma unroll
  for (int e=0;e<NEXP;e++){
    const float* g = gw + (size_t)e*HDIM + lane;
    float a = 0.f;
    #pragma unroll
    for (int i=0;i<32;i++) a += xv[i]*g[64*i];
    #pragma unroll
    for (int d=32; d>0; d>>=1) a += __shfl_xor(a, d);
    sc[e] = a;
  }
  float mx = sc[0];
  #pragma unroll
  for (int e=1;e<NEXP;e++) mx = fmaxf(mx, sc[e]);
  unsigned int mask=0; int bi[TOPK]; float bs[TOPK]; float bsum=0.f;
  #pragma unroll
  for (int k=0;k<TOPK;k++){
    float bm=-3.4e38f; int bj=0;
    #pragma unroll
    for (int e=0;e<NEXP;e++){
      bool ok = (((mask>>e)&1u)==0u) && (sc[e]>bm);
      bm = ok ? sc[e] : bm; bj = ok ? e : bj;
    }
    mask |= (1u<<bj);
    float s = expf(bm - mx);
    bi[k]=bj; bs[k]=s; bsum+=s;
  }
  if (lane==0){
    float inv = 1.f/(bsum + 1e-20f);
    #pragma unroll
    for (int k=0;k<TOPK;k++){
      topk_idx[t*TOPK+k]=bi[k];
      topk_w[t*TOPK+k]=bs[k]*inv;
      atomicAdd(&counts[bi[k]],1);
    }
  }
}

// ---------------- scan + fill dispatch lists ----------------
__global__ void scan_kernel(const int* __restrict__ counts, int* __restrict__ offsets,
                            int* __restrict__ cursor){
  int t = threadIdx.x;
  if (t < NEXP) cursor[t] = 0;
  if (t == 0){
    int s = 0;
    for (int e=0;e<NEXP;e++){ offsets[e]=s; s+=counts[e]; }
    offsets[NEXP]=s;
  }
}

__global__ __launch_bounds__(256) void fill_kernel(const int* __restrict__ topk_idx,
                                                   const float* __restrict__ topk_w,
                                                   const int* __restrict__ offsets,
                                                   int* __restrict__ cursor,
                                                   int* __restrict__ pair_token,
                                                   int* __restrict__ pos){
  int t = blockIdx.x*256 + threadIdx.x;
  if (t >= T_TOK) return;
  #pragma unroll
  for (int k=0;k<TOPK;k++){
    int e = topk_idx[t*TOPK+k];
    int c = atomicAdd(&cursor[e],1);
    int p = offsets[e]+c;
    pair_token[p]=t;
    pos[t*TOPK+k]=p;
  }
}

// ---------------- grouped GEMM, BK=64, global_load_lds + XOR swizzle ----------------
// 1-D grid, XCD-chunk swizzle: logical tile (rb fastest, then n0b, then e); all row-blocks
// sharing a B panel are consecutive-logical -> same XCD -> panel read from HBM once.
// A rows bf16 [*,K]; B [E][N][K] bf16. Tile 128x128, 4 waves 2x2.
// NB==2 EPI 0: h = silu(acc0)*acc1 -> Hout bf16. NB==1 EPI 1: acc0 -> Hout bf16 rows.
template<int NB, bool GATHER, int EPI, int NBN>
__global__ __launch_bounds__(256,2) void gemm2(
    const u16* __restrict__ Ab, const u16* __restrict__ B0, const u16* __restrict__ B1,
    u16* __restrict__ Hout,
    const int* __restrict__ counts, const int* __restrict__ offsets,
    const int* __restrict__ pair_token,
    int K, int N, int cpx)
{
  // XCD-chunk swizzle (ntile % 8 == 0 for both launches)
  const int bid = blockIdx.x;
  const int swz = (bid & 7)*cpx + (bid >> 3);
  const int rb  = swz & 31;              // 32 row-blocks, fastest
  const int rest = swz >> 5;
  const int n0b = rest % NBN;
  const int e   = rest / NBN;

  const int cnt = counts[e];
  const int row0 = rb*128;
  if (row0 >= cnt) return;
  const int off = offsets[e];
  const int n0 = n0b*128;

  __shared__ u16 smem[(1+NB)*8192];   // A | B0 | (B1)

  const int tid = threadIdx.x;
  const int lane = tid&63, wid = tid>>6;
  const int wm = wid>>1, wn = wid&1;
  const int lrow = lane&15, lgrp = lane>>4;

  // staging source pointers (swizzle baked into the global source chunk)
  const u16* ap[4]; const u16* bp0[4]; const u16* bp1[4];
  #pragma unroll
  for (int i=0;i<4;i++){
    int c = tid + 256*i;          // chunk id: row = c>>3, 16B-chunk = c&7
    int r = c>>3;
    int sc = (c&7) ^ (r&7);
    int pr = off + min(row0 + r, cnt-1);
    const u16* arow = GATHER ? (Ab + (size_t)pair_token[pr]*K) : (Ab + (size_t)pr*K);
    ap[i] = arow + sc*8;
    size_t brow = (size_t)e*N + (size_t)(n0 + r);
    bp0[i] = B0 + brow*K + sc*8;
    if (NB==2) bp1[i] = B1 + brow*K + sc*8;
  }

  // fragment LDS offsets (u16 units), swizzled to match
  int aoffs[2][4], boffs[2][4];
  #pragma unroll
  for (int kh=0;kh<2;kh++){
    #pragma unroll
    for (int f=0; f<4; f++){
      int mr = wm*64 + f*16 + lrow;
      aoffs[kh][f] = mr*64 + (((kh*4+lgrp) ^ (mr&7))*8);
      int nr = wn*64 + f*16 + lrow;
      boffs[kh][f] = nr*64 + (((kh*4+lgrp) ^ (nr&7))*8);
    }
  }

  f32x4 acc0[4][4] = {};
  f32x4 acc1[4][4] = {};

  for (int kt=0; kt<K; kt+=64){
    __syncthreads();
    #pragma unroll
    for (int i=0;i<4;i++){
      int ldo = (tid + 256*i)*8;
      gload16(ap[i] + kt, &smem[ldo]);
      gload16(bp0[i] + kt, &smem[8192 + ldo]);
      if (NB==2) gload16(bp1[i] + kt, &smem[16384 + ldo]);
    }
    __syncthreads();
    #pragma unroll
    for (int kh=0; kh<2; kh++){
      short8 af[4], b0f[4], b1f[4];
      #pragma unroll
      for (int f=0;f<4;f++){
        af[f]  = *(const short8*)&smem[aoffs[kh][f]];
        b0f[f] = *(const short8*)&smem[8192 + boffs[kh][f]];
        if (NB==2) b1f[f] = *(const short8*)&smem[16384 + boffs[kh][f]];
      }
      #pragma unroll
      for (int fm=0;fm<4;fm++){
        #pragma unroll
        for (int fn=0;fn<4;fn++){
          acc0[fm][fn] = __builtin_amdgcn_mfma_f32_16x16x32_bf16(af[fm], b0f[fn], acc0[fm][fn],0,0,0);
          if (NB==2)
            acc1[fm][fn] = __builtin_amdgcn_mfma_f32_16x16x32_bf16(af[fm], b1f[fn], acc1[fm][fn],0,0,0);
        }
      }
    }
  }

  #pragma unroll
  for (int fm=0;fm<4;fm++){
    #pragma unroll
    for (int j=0;j<4;j++){
      int grow = wm*64 + fm*16 + lgrp*4 + j;
      if (row0+grow < cnt){
        int p = off + row0 + grow;
        u16* hrow = Hout + (size_t)p*N;
        #pragma unroll
        for (int fn=0;fn<4;fn++){
          int col = n0 + wn*64 + fn*16 + lrow;
          if (EPI==0){
            float g = acc0[fm][fn][j], u = acc1[fm][fn][j];
            hrow[col] = f2bf(g*u/(1.f+expf(-g)));
          } else {
            hrow[col] = f2bf(acc0[fm][fn][j]);
          }
        }
      }
    }
  }
}

// ---------------- combine: out[t] = sum_k w[t,k] * pairbuf[pos[t,k]] ----------------
__global__ __launch_bounds__(256) void combine_kernel(const u16* __restrict__ pairbuf,
                                                      const int* __restrict__ pos,
                                                      const float* __restrict__ topk_w,
                                                      float* __restrict__ out){
  const int t = blockIdx.x;
  const int c = threadIdx.x*8;
  float acc[8] = {};
  #pragma unroll
  for (int k=0;k<TOPK;k++){
    int p = pos[t*TOPK+k];
    float w = topk_w[t*TOPK+k];
    uint4 v = *(const uint4*)&pairbuf[(size_t)p*HDIM + c];
    unsigned int ws_[4] = {v.x,v.y,v.z,v.w};
    #pragma unroll
    for (int j=0;j<4;j++){
      acc[2*j]   += w*bf2f(ws_[j]&0xffffu);
      acc[2*j+1] += w*bf2f(ws_[j]>>16);
    }
  }
  float4 o0 = {acc[0],acc[1],acc[2],acc[3]};
  float4 o1 = {acc[4],acc[5],acc[6],acc[7]};
  float* orow = out + (size_t)t*HDIM + c;
  *(float4*)orow = o0;
  *(float4*)(orow+4) = o1;
}

extern "C" void kernel_launch(void* const* d_in, const int* in_sizes, int n_in,
                              void* d_out, int out_size, void* d_ws, size_t ws_size,
                              hipStream_t stream) {
  const float* x  = (const float*)d_in[0];
  const float* gw = (const float*)d_in[1];
  const float* wg = (const float*)d_in[2];
  const float* wu = (const float*)d_in[3];
  const float* wd = (const float*)d_in[4];
  float* out = (float*)d_out;

  const size_t WT_BYTES = (size_t)NEXP*MDIM*HDIM*2;  // 161,480,704

  char* p = (char*)d_ws;
  u16* wg_t = (u16*)p;                 // [E][M][H] bf16
  u16* wd_t = (u16*)p;                 // [E][H][M] bf16 (overwrites wg_t after stage 1)
  p += WT_BYTES;
  u16* wu_t    = (u16*)p;              // [E][M][H] bf16
  u16* pairbuf = (u16*)p;              // [NPAIR][H] bf16 (overlays dead wu_t)
  p += WT_BYTES;
  u16* xb   = (u16*)p; p += (size_t)T_TOK*HDIM*2;   // 16.8 MB
  u16* hbuf = (u16*)p; p += (size_t)NPAIR*MDIM*2;   // 69.2 MB
  int*   topk_idx   = (int*)p;   p += NPAIR*4;
  float* topk_w     = (float*)p; p += NPAIR*4;
  int*   pair_token = (int*)p;   p += NPAIR*4;
  int*   pos        = (int*)p;   p += NPAIR*4;
  int*   counts     = (int*)p;   p += 128;
  int*   offsets    = (int*)p;   p += 128;
  int*   cursor     = (int*)p;   p += 128;

  hipMemsetAsync(counts, 0, 128, stream);
  cvt_kernel<<<T_TOK*HDIM/8/256, 256, 0, stream>>>(x, xb, T_TOK*HDIM/8);
  gate_kernel<<<T_TOK/4, 256, 0, stream>>>(x, gw, topk_idx, topk_w, counts);
  scan_kernel<<<1, 64, 0, stream>>>(counts, offsets, cursor);
  fill_kernel<<<T_TOK/256, 256, 0, stream>>>(topk_idx, topk_w, offsets, cursor, pair_token, pos);

  // weights -> bf16 transposed
  transpose_cvt<<<dim3(MDIM/64, HDIM/64, NEXP), 256, 0, stream>>>(wg, wg_t, HDIM, MDIM);
  transpose_cvt<<<dim3(MDIM/64, HDIM/64, NEXP), 256, 0, stream>>>(wu, wu_t, HDIM, MDIM);

  // stage 1: h = silu(x@wg) * (x@wu)   — ntile = 32*11*28 = 9856 (9856%8==0)
  {
    int ntile = 32*(MDIM/128)*NEXP;
    gemm2<2,true,0,(MDIM/128)><<<ntile, 256, 0, stream>>>(
        xb, wg_t, wu_t, hbuf, counts, offsets, pair_token, HDIM, MDIM, ntile/8);
  }

  // wd -> bf16 transposed (reuses wg_t space; stream-ordered after stage 1)
  transpose_cvt<<<dim3(HDIM/64, MDIM/64, NEXP), 256, 0, stream>>>(wd, wd_t, MDIM, HDIM);

  // stage 2: pairbuf = h @ wd  — ntile = 32*16*28 = 14336 (14336%8==0)
  {
    int ntile = 32*(HDIM/128)*NEXP;
    gemm2<1,false,1,(HDIM/128)><<<ntile, 256, 0, stream>>>(
        hbuf, wd_t, nullptr, pairbuf, counts, offsets, pair_token, MDIM, HDIM, ntile/8);
  }

  // combine: out[t] = sum_k w_k * pairbuf[pos[t,k]]
  combine_kernel<<<T_TOK, 256, 0, stream>>>(pairbuf, pos, topk_w, out);
}